// Round 10
// baseline (523.240 us; speedup 1.0000x reference)
//
#include <hip/hip_runtime.h>
#include <cmath>
#include <cfloat>

#define DEV __device__ __forceinline__

DEV unsigned enc_f(float x) { unsigned u = __float_as_uint(x); return (u >> 31) ? ~u : (u | 0x80000000u); }
DEV float dec_f(unsigned u) { return __uint_as_float((u >> 31) ? (u & 0x7FFFFFFFu) : ~u); }

// ---------------- merged launch 1: layer-0 GEMM + XCD-partitioned count+rank + encoder -------
__global__ __launch_bounds__(256) void fused0_kernel(
    const int* __restrict__ dst, int* __restrict__ deg, int* __restrict__ rank, int E, int N,
    const float* __restrict__ A, const float* __restrict__ B1, const float* __restrict__ B2,
    float* __restrict__ O1, float* __restrict__ O2, int nGemm, int nCount,
    const int* __restrict__ ids, const float* __restrict__ rssi,
    const float* __restrict__ emb, const float* __restrict__ ew, const float* __restrict__ eb,
    const float* __restrict__ b0, float* __restrict__ zout, int NQ)
{
    __shared__ float As[64][36];    // 9.2 KB
    __shared__ float Bs[32][128];   // 16.4 KB

    if (blockIdx.x >= (unsigned)nGemm) {
        if (blockIdx.x < (unsigned)(nGemm + nCount)) {
            // ---- count + rank role (XCD-partitioned by dst range)
            const int cbid = blockIdx.x - nGemm;
            const int part = cbid & 7;
            const int chunk = cbid >> 3;
            const int npart = (N + 7) >> 3;
            const int lo = part * npart;
            const int hi = min(lo + npart, N);
            const int base = chunk * 4096 + threadIdx.x;
#pragma unroll
            for (int it = 0; it < 16; ++it) {
                int i = base + it * 256;
                if (i < E) {
                    int d = dst[i];
                    if (d >= lo && d < hi) rank[i] = atomicAdd(&deg[d], 1);
                }
            }
            return;
        }
        // ---- encoder role (1 block); zsh/zq aliased into As
        float (*zsh)[64] = (float(*)[64])&As[0][0];
        float* zq = &As[16][0];
        int j = threadIdx.x & 63;
        int g = threadIdx.x >> 6;
        float acc = 0.f;
        for (int q = g; q < NQ; q += 4) {
            int id = ids[q];
            const float* e = emb + (size_t)id * 32;
            float p = eb[j];
#pragma unroll
            for (int k = 0; k < 32; ++k) p = fmaf(e[k], ew[k * 64 + j], p);
            p = fmaf(rssi[q], ew[32 * 64 + j], p);
            acc += fmaxf(p, 0.f);
        }
        zsh[g][j] = acc;
        __syncthreads();
        if (g == 0) {
            float z = (zsh[0][j] + zsh[1][j] + zsh[2][j] + zsh[3][j]) / (float)NQ;
            zq[j] = z;
            zout[j] = z;
        }
        __syncthreads();
        if (g == 0) {
            float cl = 0.f, cr = 0.f;
            for (int k = 0; k < 64; ++k) {
                float zk = zq[k];
                cl = fmaf(zk, B1[(128 + k) * 64 + j], cl);
                cr = fmaf(zk, B2[(128 + k) * 64 + j], cr);
            }
            zout[64 + j] = cl;            // cl
            zout[128 + j] = cr + b0[j];   // crb
        }
        return;
    }

    // ---- gemm0 role: 64-row dual GEMM, K=128, RAW outputs (bias/crb added later in agg)
    const int tid = threadIdx.x;
    const int cg = tid & 15;
    const int rg = tid >> 4;
    const int row0 = blockIdx.x * 64;

    float acc[4][8];
#pragma unroll
    for (int i = 0; i < 4; ++i)
#pragma unroll
        for (int j = 0; j < 8; ++j) acc[i][j] = 0.f;

    for (int kc = 0; kc < 128; kc += 32) {
#pragma unroll
        for (int i = 0; i < 2; ++i) {
            int vi = i * 256 + tid;
            int r = vi >> 3;
            int k4 = (vi & 7) << 2;
            int row = row0 + r;
            float4 v = make_float4(0.f, 0.f, 0.f, 0.f);
            if (row < N) v = *(const float4*)(A + (size_t)row * 128 + kc + k4);
            *(float4*)&As[r][k4] = v;
        }
#pragma unroll
        for (int i = 0; i < 4; ++i) {
            int vi = i * 256 + tid;
            int k = vi >> 5;
            int c = (vi & 31) << 2;
            const float* sp = (c < 64) ? (B1 + (size_t)(kc + k) * 64 + c)
                                       : (B2 + (size_t)(kc + k) * 64 + (c - 64));
            *(float4*)&Bs[k][c] = *(const float4*)sp;
        }
        __syncthreads();
#pragma unroll
        for (int k4 = 0; k4 < 32; k4 += 4) {
            float4 a4[4];
#pragma unroll
            for (int i = 0; i < 4; ++i)
                a4[i] = *(const float4*)&As[rg * 4 + i][k4];
#pragma unroll
            for (int j = 0; j < 4; ++j) {
                float4 b0v = *(const float4*)&Bs[k4 + j][cg * 8];
                float4 b1v = *(const float4*)&Bs[k4 + j][cg * 8 + 4];
#pragma unroll
                for (int i = 0; i < 4; ++i) {
                    float av = ((const float*)&a4[i])[j];
                    acc[i][0] = fmaf(av, b0v.x, acc[i][0]);
                    acc[i][1] = fmaf(av, b0v.y, acc[i][1]);
                    acc[i][2] = fmaf(av, b0v.z, acc[i][2]);
                    acc[i][3] = fmaf(av, b0v.w, acc[i][3]);
                    acc[i][4] = fmaf(av, b1v.x, acc[i][4]);
                    acc[i][5] = fmaf(av, b1v.y, acc[i][5]);
                    acc[i][6] = fmaf(av, b1v.z, acc[i][6]);
                    acc[i][7] = fmaf(av, b1v.w, acc[i][7]);
                }
            }
        }
        __syncthreads();
    }

    int c0 = cg * 8;
    float* O; int c;
    if (c0 < 64) { O = O1; c = c0; }
    else         { O = O2; c = c0 - 64; }
#pragma unroll
    for (int i = 0; i < 4; ++i) {
        int row = row0 + rg * 4 + i;
        if (row < N) {
            float4 o0 = make_float4(acc[i][0], acc[i][1], acc[i][2], acc[i][3]);
            float4 o1 = make_float4(acc[i][4], acc[i][5], acc[i][6], acc[i][7]);
            *(float4*)(O + (size_t)row * 64 + c) = o0;
            *(float4*)(O + (size_t)row * 64 + c + 4) = o1;
        }
    }
}

// ---------------- CSR build: scanA (local) + scanC (per-block prefix of bsum) ----------------
__global__ __launch_bounds__(256) void scanA_kernel(const int* __restrict__ deg, int* __restrict__ offs,
                                                    int* __restrict__ bsum, unsigned* __restrict__ red, int N)
{
    __shared__ int sh[256];
    int t = threadIdx.x;
    if (blockIdx.x == 0 && t < 8) red[t] = 0u;
    int i = blockIdx.x * 256 + t;
    int v = (i < N) ? deg[i] : 0;
    sh[t] = v;
    __syncthreads();
#pragma unroll
    for (int d = 1; d < 256; d <<= 1) {
        int u = (t >= d) ? sh[t - d] : 0;
        __syncthreads();
        sh[t] += u;
        __syncthreads();
    }
    if (i < N) offs[i] = sh[t] - v;
    if (t == 255) bsum[blockIdx.x] = sh[255];
}

__global__ __launch_bounds__(256) void scanC_kernel(int* __restrict__ offs, const int* __restrict__ bsum,
                                                    int N, int NB)
{
    __shared__ int sh[256];
    int t = threadIdx.x;
    int bid = blockIdx.x;
    int s = 0;
    for (int j = t; j < bid; j += 256) s += bsum[j];
    sh[t] = s;
    __syncthreads();
#pragma unroll
    for (int d = 128; d >= 1; d >>= 1) {
        if (t < d) sh[t] += sh[t + d];
        __syncthreads();
    }
    int base = sh[0];
    int i = bid * 256 + t;
    if (i < N) offs[i] += base;
    if (bid == NB - 1 && t == 0) offs[N] = base + bsum[NB - 1];
}

// ---------------- atomic-free scatter: srcs[offs[d]+rank[i]] = src[i] (pure stream) ----------
__global__ __launch_bounds__(256) void scatter_kernel(const int* __restrict__ src, const int* __restrict__ dst,
                                                      const int* __restrict__ rank, const int* __restrict__ offs,
                                                      int* __restrict__ srcs, int E)
{
    int i = blockIdx.x * 1024 + threadIdx.x;
#pragma unroll
    for (int it = 0; it < 4; ++it, i += 256) {
        if (i < E) srcs[offs[dst[i]] + rank[i]] = src[i];
    }
}

// ---------------- layer-0 aggregation (float4 16-lane gather, no LDS) -- unchanged (control) -
__global__ __launch_bounds__(256) void agg_kernel(
    const float* __restrict__ m, const float* __restrict__ r,
    const int* __restrict__ off, const int* __restrict__ srcs,
    const float* __restrict__ cl, const float* __restrict__ crb,
    float* __restrict__ hout, int N)
{
    const int tid = threadIdx.x;
    const int lane = tid & 63;
    const int wave = tid >> 6;
    const int grp = lane >> 4;
    const int l16 = lane & 15;
    const int node0 = blockIdx.x * 64;

    int offv = off[min(node0 + lane, N)];
    int offend = off[min(node0 + 64, N)];
    float4 cl4 = *(const float4*)(cl + l16 * 4);
    float4 cb4 = *(const float4*)(crb + l16 * 4);

    int e0p = __shfl(offv, wave);
    int e1p = (wave < 63) ? __shfl(offv, wave + 1) : offend;
    int sv = (e0p + lane < e1p) ? srcs[e0p + lane] : 0;

    for (int idx = 0; idx < 16; ++idx) {
        int nn = wave + idx * 4;
        int node = node0 + nn;
        int e0 = __shfl(offv, nn);
        int e1 = (nn < 63) ? __shfl(offv, nn + 1) : offend;
        int cur_sv = sv;
        if (idx < 15) {
            int nx = nn + 4;
            int ne0 = __shfl(offv, nx);
            int ne1 = (nx < 63) ? __shfl(offv, nx + 1) : offend;
            sv = (ne0 + lane < ne1) ? srcs[ne0 + lane] : 0;
        }
        float4 r4 = make_float4(0.f, 0.f, 0.f, 0.f);
        if (node < N) r4 = *((const float4*)(r + (size_t)node * 64) + l16);

        float4 acc4[4];
#pragma unroll
        for (int t = 0; t < 4; ++t) acc4[t] = make_float4(0.f, 0.f, 0.f, 0.f);

        for (int base = e0; base < e1; base += 64) {
            int cnt = min(e1 - base, 64);
            int svs = (base == e0) ? cur_sv : ((base + lane < e1) ? srcs[base + lane] : 0);
            for (int u = 0; u < cnt; u += 16) {
#pragma unroll
                for (int t = 0; t < 4; ++t) {
                    int ei = u + t * 4 + grp;
                    int s = __shfl(svs, ei);
                    if (ei < cnt) {
                        float4 v = *((const float4*)(m + (size_t)s * 64) + l16);
                        acc4[t].x += v.x; acc4[t].y += v.y;
                        acc4[t].z += v.z; acc4[t].w += v.w;
                    }
                }
            }
        }
        float4 tot;
        tot.x = (acc4[0].x + acc4[1].x) + (acc4[2].x + acc4[3].x);
        tot.y = (acc4[0].y + acc4[1].y) + (acc4[2].y + acc4[3].y);
        tot.z = (acc4[0].z + acc4[1].z) + (acc4[2].z + acc4[3].z);
        tot.w = (acc4[0].w + acc4[1].w) + (acc4[2].w + acc4[3].w);
        tot.x += __shfl_xor(tot.x, 16); tot.x += __shfl_xor(tot.x, 32);
        tot.y += __shfl_xor(tot.y, 16); tot.y += __shfl_xor(tot.y, 32);
        tot.z += __shfl_xor(tot.z, 16); tot.z += __shfl_xor(tot.z, 32);
        tot.w += __shfl_xor(tot.w, 16); tot.w += __shfl_xor(tot.w, 32);

        int deg = e1 - e0;
        float inv = 1.f / (float)(deg > 0 ? deg : 1);
        if (lane < 16 && node < N) {
            float cadd = (deg > 0) ? 1.f : 0.f;
            float4 o;
            o.x = fmaxf(fmaf(tot.x, inv, fmaf(cadd, cl4.x, r4.x + cb4.x)), 0.f);
            o.y = fmaxf(fmaf(tot.y, inv, fmaf(cadd, cl4.y, r4.y + cb4.y)), 0.f);
            o.z = fmaxf(fmaf(tot.z, inv, fmaf(cadd, cl4.z, r4.z + cb4.z)), 0.f);
            o.w = fmaxf(fmaf(tot.w, inv, fmaf(cadd, cl4.w, r4.w + cb4.w)), 0.f);
            *(float4*)(hout + (size_t)node * 64 + l16 * 4) = o;
        }
    }
}

// ---------------- fused SAGE layer (layers 1-2): L2-chunked 4-pass gather --------------------
// r8 diagnosis: gather was random-fine-grain HBM/L3 bound (FETCH 78MB >> 12.8MB working set,
// HBM at 1.08 TB/s). 4 passes over source-id chunks of N/4 (3.2MB < 4MB L2/XCD); all ~1536
// blocks co-resident -> during pass p every L2 holds chunk p; partials parked in As (rows
// owned per-wave, no extra barriers). Phase 2 and occupancy shape identical to round 8.
template <bool SCORER>
__global__ __launch_bounds__(256) void sage_fused_kernel(
    const float* __restrict__ h,
    const int* __restrict__ off, const int* __restrict__ srcs,
    const float* __restrict__ Wl, const float* __restrict__ Wr, const float* __restrict__ bias,
    const float* __restrict__ sw1, const float* __restrict__ sb1,
    const float* __restrict__ sw2, const float* __restrict__ sb2,
    float* __restrict__ hout, float* __restrict__ sbuf, unsigned* __restrict__ red, int N)
{
    __shared__ float As[32][132];   // 16.9 KB
    __shared__ float Bs[32][64];    // 8 KB
    __shared__ float smax_sh[256];  // 1 KB

    const int tid = threadIdx.x;
    const int lane = tid & 63;
    const int wave = tid >> 6;
    const int grp = lane >> 4;
    const int l16 = lane & 15;
    const int node0 = blockIdx.x * 32;

    int offv = off[min(node0 + lane, N)];   // lanes 0..32 used

    // ---- Phase 1: 4-pass gather, pass p touches only src rows in chunk p (L2-resident)
    const int NPASS = 4;
    const int chunkN = (N + NPASS - 1) / NPASS;

    for (int pass = 0; pass < NPASS; ++pass) {
        const unsigned plo = (unsigned)(pass * chunkN);

        for (int idx = 0; idx < 8; ++idx) {
            int nn = wave + idx * 4;
            int e0 = __shfl(offv, nn);
            int e1 = __shfl(offv, nn + 1);

            float4 acc4[4];
#pragma unroll
            for (int t = 0; t < 4; ++t) acc4[t] = make_float4(0.f, 0.f, 0.f, 0.f);

            for (int base = e0; base < e1; base += 64) {
                int cnt = min(e1 - base, 64);
                int svs = (base + lane < e1) ? srcs[base + lane] : 0;
                for (int u = 0; u < cnt; u += 16) {
#pragma unroll
                    for (int t = 0; t < 4; ++t) {
                        int ei = u + t * 4 + grp;
                        int s = __shfl(svs, ei);
                        if (ei < cnt && (unsigned)(s - plo) < (unsigned)chunkN) {
                            float4 v = *((const float4*)(h + (size_t)s * 64) + l16);
                            acc4[t].x += v.x; acc4[t].y += v.y;
                            acc4[t].z += v.z; acc4[t].w += v.w;
                        }
                    }
                }
            }
            float4 tot;
            tot.x = (acc4[0].x + acc4[1].x) + (acc4[2].x + acc4[3].x);
            tot.y = (acc4[0].y + acc4[1].y) + (acc4[2].y + acc4[3].y);
            tot.z = (acc4[0].z + acc4[1].z) + (acc4[2].z + acc4[3].z);
            tot.w = (acc4[0].w + acc4[1].w) + (acc4[2].w + acc4[3].w);
            tot.x += __shfl_xor(tot.x, 16); tot.x += __shfl_xor(tot.x, 32);
            tot.y += __shfl_xor(tot.y, 16); tot.y += __shfl_xor(tot.y, 32);
            tot.z += __shfl_xor(tot.z, 16); tot.z += __shfl_xor(tot.z, 32);
            tot.w += __shfl_xor(tot.w, 16); tot.w += __shfl_xor(tot.w, 32);

            if (lane < 16) {
                float4* p = (float4*)&As[nn][l16 * 4];
                if (pass == 0) {
                    *p = tot;                  // uniform branch (scalar pass)
                } else {
                    float4 old = *p;
                    old.x += tot.x; old.y += tot.y; old.z += tot.z; old.w += tot.w;
                    *p = old;
                }
            }
        }
    }

    // ---- epilogue of phase 1: scale by 1/deg, stage own-h row
    for (int idx = 0; idx < 8; ++idx) {
        int nn = wave + idx * 4;
        int node = node0 + nn;
        int e0 = __shfl(offv, nn);
        int e1 = __shfl(offv, nn + 1);
        int deg = e1 - e0;
        float inv = 1.f / (float)(deg > 0 ? deg : 1);
        if (lane < 16) {
            float4 g = *(float4*)&As[nn][l16 * 4];
            g.x *= inv; g.y *= inv; g.z *= inv; g.w *= inv;
            *(float4*)&As[nn][l16 * 4] = g;
            float4 hv = make_float4(0.f, 0.f, 0.f, 0.f);
            if (node < N) hv = *((const float4*)(h + (size_t)node * 64) + l16);
            *(float4*)&As[nn][64 + l16 * 4] = hv;
        }
    }
    __syncthreads();

    // ---- Phase 2: [32x128] @ [128x64], thread tile 2 rows x 4 cols (round-8 verbatim)
    const int cg = tid & 15;
    const int rg = tid >> 4;
    float acc[2][4];
#pragma unroll
    for (int i = 0; i < 2; ++i)
#pragma unroll
        for (int j = 0; j < 4; ++j) acc[i][j] = 0.f;

    for (int kc = 0; kc < 128; kc += 32) {
#pragma unroll
        for (int i = 0; i < 2; ++i) {
            int vi = i * 256 + tid;
            int k = vi >> 4;
            int c = (vi & 15) << 2;
            int kg = kc + k;
            const float* wp = (kg < 64) ? (Wl + (size_t)kg * 64 + c)
                                        : (Wr + (size_t)(kg - 64) * 64 + c);
            *(float4*)&Bs[k][c] = *(const float4*)wp;
        }
        __syncthreads();
#pragma unroll
        for (int k4 = 0; k4 < 32; k4 += 4) {
            float4 a4[2];
#pragma unroll
            for (int i = 0; i < 2; ++i)
                a4[i] = *(const float4*)&As[rg * 2 + i][kc + k4];   // broadcast
#pragma unroll
            for (int j = 0; j < 4; ++j) {
                float4 bv = *(const float4*)&Bs[k4 + j][cg * 4];
#pragma unroll
                for (int i = 0; i < 2; ++i) {
                    float av = ((const float*)&a4[i])[j];
                    acc[i][0] = fmaf(av, bv.x, acc[i][0]);
                    acc[i][1] = fmaf(av, bv.y, acc[i][1]);
                    acc[i][2] = fmaf(av, bv.z, acc[i][2]);
                    acc[i][3] = fmaf(av, bv.w, acc[i][3]);
                }
            }
        }
        __syncthreads();
    }

    float4 b4 = *(const float4*)(bias + cg * 4);

    if (!SCORER) {
#pragma unroll
        for (int i = 0; i < 2; ++i) {
            int row = node0 + rg * 2 + i;
            if (row < N) {
                float4 o;
                o.x = fmaxf(acc[i][0] + b4.x, 0.f);
                o.y = fmaxf(acc[i][1] + b4.y, 0.f);
                o.z = fmaxf(acc[i][2] + b4.z, 0.f);
                o.w = fmaxf(acc[i][3] + b4.w, 0.f);
                *(float4*)(hout + (size_t)row * 64 + cg * 4) = o;
            }
        }
        return;
    }

    // ---- SCORER: h2 -> As cols 0..63, then s = relu(h2@w1+b1)@w2 + b2 (h2 never hits HBM)
#pragma unroll
    for (int i = 0; i < 2; ++i) {
        float4 t;
        t.x = fmaxf(acc[i][0] + b4.x, 0.f);
        t.y = fmaxf(acc[i][1] + b4.y, 0.f);
        t.z = fmaxf(acc[i][2] + b4.z, 0.f);
        t.w = fmaxf(acc[i][3] + b4.w, 0.f);
        *(float4*)&As[rg * 2 + i][cg * 4] = t;
    }
    __syncthreads();

    float acc2[2][4];
#pragma unroll
    for (int i = 0; i < 2; ++i)
#pragma unroll
        for (int j = 0; j < 4; ++j) acc2[i][j] = 0.f;

    for (int kc = 0; kc < 64; kc += 32) {
#pragma unroll
        for (int i = 0; i < 2; ++i) {
            int vi = i * 256 + tid;
            int k = vi >> 4;
            int c = (vi & 15) << 2;
            *(float4*)&Bs[k][c] = *(const float4*)(sw1 + (size_t)(kc + k) * 64 + c);
        }
        __syncthreads();
#pragma unroll
        for (int k4 = 0; k4 < 32; k4 += 4) {
            float4 a4[2];
#pragma unroll
            for (int i = 0; i < 2; ++i)
                a4[i] = *(const float4*)&As[rg * 2 + i][kc + k4];
#pragma unroll
            for (int j = 0; j < 4; ++j) {
                float4 bv = *(const float4*)&Bs[k4 + j][cg * 4];
#pragma unroll
                for (int i = 0; i < 2; ++i) {
                    float av = ((const float*)&a4[i])[j];
                    acc2[i][0] = fmaf(av, bv.x, acc2[i][0]);
                    acc2[i][1] = fmaf(av, bv.y, acc2[i][1]);
                    acc2[i][2] = fmaf(av, bv.z, acc2[i][2]);
                    acc2[i][3] = fmaf(av, bv.w, acc2[i][3]);
                }
            }
        }
        __syncthreads();
    }

    float4 s1b = *(const float4*)(sb1 + cg * 4);
    float4 w24 = *(const float4*)(sw2 + cg * 4);
    float bb = sb2[0];
    float svals[2];
#pragma unroll
    for (int i = 0; i < 2; ++i) {
        float p = fmaxf(acc2[i][0] + s1b.x, 0.f) * w24.x;
        p = fmaf(fmaxf(acc2[i][1] + s1b.y, 0.f), w24.y, p);
        p = fmaf(fmaxf(acc2[i][2] + s1b.z, 0.f), w24.z, p);
        p = fmaf(fmaxf(acc2[i][3] + s1b.w, 0.f), w24.w, p);
#pragma unroll
        for (int d = 1; d <= 8; d <<= 1) p += __shfl_xor(p, d, 64);
        svals[i] = p;
    }
    float smx = -FLT_MAX;
    if (cg == 0) {
#pragma unroll
        for (int i = 0; i < 2; ++i) {
            int row = node0 + rg * 2 + i;
            if (row < N) {
                float s = svals[i] + bb;
                sbuf[row] = s;
                smx = fmaxf(smx, s);
            }
        }
    }
    smax_sh[tid] = smx;
    __syncthreads();
    for (int d = 128; d >= 1; d >>= 1) {
        if (tid < d) smax_sh[tid] = fmaxf(smax_sh[tid], smax_sh[tid + d]);
        __syncthreads();
    }
    if (tid == 0) atomicMax(red, enc_f(smax_sh[0]));
}

// ---------------- softmax: sum + finalize in ONE kernel (ticket spin, 128 resident blocks) ----
__global__ __launch_bounds__(256) void sumfinal_kernel(const float* __restrict__ s, const float* __restrict__ pos,
                                                       unsigned* __restrict__ red, float* __restrict__ out, int N)
{
    float mx = dec_f(red[0]);
    float se = 0.f, px = 0.f, py = 0.f;
    for (int i = blockIdx.x * blockDim.x + threadIdx.x; i < N; i += gridDim.x * blockDim.x) {
        float e = expf(s[i] - mx);
        se += e;
        px = fmaf(e, pos[2 * i], px);
        py = fmaf(e, pos[2 * i + 1], py);
    }
#pragma unroll
    for (int d = 32; d >= 1; d >>= 1) {
        se += __shfl_xor(se, d, 64);
        px += __shfl_xor(px, d, 64);
        py += __shfl_xor(py, d, 64);
    }
    if ((threadIdx.x & 63) == 0) {
        atomicAdd((float*)red + 1, se);
        atomicAdd((float*)red + 2, px);
        atomicAdd((float*)red + 3, py);
    }
    __threadfence();
    if (threadIdx.x == 0) {
        __hip_atomic_fetch_add(&red[4], 1u, __ATOMIC_ACQ_REL, __HIP_MEMORY_SCOPE_AGENT);
        while (__hip_atomic_load(&red[4], __ATOMIC_ACQUIRE, __HIP_MEMORY_SCOPE_AGENT) < (unsigned)gridDim.x) {}
    }
    __syncthreads();
    float S  = __uint_as_float(__hip_atomic_load(&red[1], __ATOMIC_RELAXED, __HIP_MEMORY_SCOPE_AGENT));
    float PX = __uint_as_float(__hip_atomic_load(&red[2], __ATOMIC_RELAXED, __HIP_MEMORY_SCOPE_AGENT));
    float PY = __uint_as_float(__hip_atomic_load(&red[3], __ATOMIC_RELAXED, __HIP_MEMORY_SCOPE_AGENT));
    float invS = 1.f / S;
    for (int i = blockIdx.x * blockDim.x + threadIdx.x; i < N; i += gridDim.x * blockDim.x)
        out[2 + i] = expf(s[i] - mx) * invS;
    if (blockIdx.x == 0 && threadIdx.x == 0) {
        out[0] = PX * invS;
        out[1] = PY * invS;
    }
}

extern "C" void kernel_launch(void* const* d_in, const int* in_sizes, int n_in,
                              void* d_out, int out_size, void* d_ws, size_t ws_size,
                              hipStream_t stream)
{
    const float* x    = (const float*)d_in[0];
    const float* pos  = (const float*)d_in[1];
    const int*   ei   = (const int*)d_in[2];
    const int*   qids = (const int*)d_in[3];
    const float* qrs  = (const float*)d_in[4];
    const float* emb  = (const float*)d_in[5];
    const float* ew   = (const float*)d_in[6];
    const float* eb   = (const float*)d_in[7];
    const float* Wl0  = (const float*)d_in[8];
    const float* Wr0  = (const float*)d_in[9];
    const float* b0   = (const float*)d_in[10];
    const float* Wl1  = (const float*)d_in[11];
    const float* Wr1  = (const float*)d_in[12];
    const float* b1   = (const float*)d_in[13];
    const float* Wl2  = (const float*)d_in[14];
    const float* Wr2  = (const float*)d_in[15];
    const float* b2   = (const float*)d_in[16];
    const float* sw1  = (const float*)d_in[17];
    const float* sb1  = (const float*)d_in[18];
    const float* sw2  = (const float*)d_in[19];
    const float* sb2  = (const float*)d_in[20];

    const int N  = in_sizes[0] / 128;
    const int E  = in_sizes[2] / 2;
    const int NQ = in_sizes[3];
    const int NB = (N + 255) / 256;

    char* base = (char*)d_ws;
    size_t wsoff = 0;
    auto take = [&](size_t bytes) -> char* {
        char* p = base + wsoff;
        wsoff = (wsoff + bytes + 255) & ~(size_t)255;
        return p;
    };
    int*      deg    = (int*)take((size_t)N * 4);
    int*      offs   = (int*)take((size_t)(N + 1) * 4);
    int*      rank   = (int*)take((size_t)E * 4);
    int*      bsum   = (int*)take((size_t)NB * 4);
    int*      srcs   = (int*)take((size_t)E * 4);
    float*    zout   = (float*)take(192 * 4);   // zq[64], cl[64], crb[64]
    unsigned* red    = (unsigned*)take(32);     // [0]=max [1]=sumexp [2]=px [3]=py [4]=ticket
    float*    mbuf   = (float*)take((size_t)N * 64 * 4);
    float*    rbuf   = (float*)take((size_t)N * 64 * 4);
    float*    hbuf   = (float*)take((size_t)N * 64 * 4);
    float*    sbuf   = (float*)take((size_t)N * 4);
    (void)ws_size; (void)n_in; (void)out_size;

    const int* esrc = ei;
    const int* edst = ei + E;

    hipMemsetAsync(deg, 0, (size_t)N * 4, stream);

    int schunks = (E + 4095) / 4096;
    int nCount = schunks * 8;
    int g64 = (N + 63) / 64;
    int g32 = (N + 31) / 32;

    // launch 1: gemm0 (independent) + count+rank (atomic-bound) + encoder, overlapped
    fused0_kernel<<<g64 + nCount + 1, 256, 0, stream>>>(edst, deg, rank, E, N,
                                                        x, Wl0, Wr0, mbuf, rbuf, g64, nCount,
                                                        qids, qrs, emb, ew, eb, b0, zout, NQ);
    scanA_kernel<<<NB, 256, 0, stream>>>(deg, offs, bsum, red, N);
    scanC_kernel<<<NB, 256, 0, stream>>>(offs, bsum, N, NB);
    // atomic-free scatter (pure stream)
    scatter_kernel<<<(E + 1023) / 1024, 256, 0, stream>>>(esrc, edst, rank, offs, srcs, E);
    // layer 0 aggregation (adds crb + cl here; gemm0 wrote raw products)
    agg_kernel<<<g64, 256, 0, stream>>>(mbuf, rbuf, offs, srcs, zout + 64, zout + 128, hbuf, N);
    // layer 1: fused agg-first + gemm (hbuf -> mbuf)
    sage_fused_kernel<false><<<g32, 256, 0, stream>>>(hbuf, offs, srcs, Wl1, Wr1, b1,
                                                      nullptr, nullptr, nullptr, nullptr,
                                                      mbuf, nullptr, nullptr, N);
    // layer 2 + scorer fused (mbuf -> sbuf, red[0])
    sage_fused_kernel<true><<<g32, 256, 0, stream>>>(mbuf, offs, srcs, Wl2, Wr2, b2,
                                                     sw1, sb1, sw2, sb2,
                                                     nullptr, sbuf, red, N);
    // softmax sum + finalize (single launch, internal grid sync)
    sumfinal_kernel<<<128, 256, 0, stream>>>(sbuf, pos, red, (float*)d_out, N);
}

// Round 11
// 377.304 us; speedup vs baseline: 1.3868x; 1.3868x over previous
//
#include <hip/hip_runtime.h>
#include <hip/hip_fp16.h>
#include <cmath>
#include <cfloat>

#define DEV __device__ __forceinline__

DEV unsigned enc_f(float x) { unsigned u = __float_as_uint(x); return (u >> 31) ? ~u : (u | 0x80000000u); }
DEV float dec_f(unsigned u) { return __uint_as_float((u >> 31) ? (u & 0x7FFFFFFFu) : ~u); }

// 4 halves packed in a float2 <-> float4 converters
DEV float4 h4_to_f4(float2 raw) {
    __half2 a = *(__half2*)&raw.x, b = *(__half2*)&raw.y;
    float2 fa = __half22float2(a), fb = __half22float2(b);
    return make_float4(fa.x, fa.y, fb.x, fb.y);
}
DEV float2 f4_to_h4(float4 v) {
    __half2 a = __floats2half2_rn(v.x, v.y), b = __floats2half2_rn(v.z, v.w);
    float2 r; *(__half2*)&r.x = a; *(__half2*)&r.y = b; return r;
}

// ---------------- merged launch 1: layer-0 GEMM + XCD-partitioned count+rank + encoder -------
// gemm0 writes RAW products as fp16 (O1=x@Wl0top, O2=x@Wr0top); bias/crb added in agg.
__global__ __launch_bounds__(256) void fused0_kernel(
    const int* __restrict__ dst, int* __restrict__ deg, int* __restrict__ rank, int E, int N,
    const float* __restrict__ A, const float* __restrict__ B1, const float* __restrict__ B2,
    __half* __restrict__ O1, __half* __restrict__ O2, int nGemm, int nCount,
    const int* __restrict__ ids, const float* __restrict__ rssi,
    const float* __restrict__ emb, const float* __restrict__ ew, const float* __restrict__ eb,
    const float* __restrict__ b0, float* __restrict__ zout, int NQ)
{
    __shared__ float As[64][36];    // 9.2 KB
    __shared__ float Bs[32][128];   // 16.4 KB

    if (blockIdx.x >= (unsigned)nGemm) {
        if (blockIdx.x < (unsigned)(nGemm + nCount)) {
            // ---- count + rank role (XCD-partitioned by dst range)
            const int cbid = blockIdx.x - nGemm;
            const int part = cbid & 7;
            const int chunk = cbid >> 3;
            const int npart = (N + 7) >> 3;
            const int lo = part * npart;
            const int hi = min(lo + npart, N);
            const int base = chunk * 4096 + threadIdx.x;
#pragma unroll
            for (int it = 0; it < 16; ++it) {
                int i = base + it * 256;
                if (i < E) {
                    int d = dst[i];
                    if (d >= lo && d < hi) rank[i] = atomicAdd(&deg[d], 1);
                }
            }
            return;
        }
        // ---- encoder role (1 block); zsh/zq aliased into As
        float (*zsh)[64] = (float(*)[64])&As[0][0];
        float* zq = &As[16][0];
        int j = threadIdx.x & 63;
        int g = threadIdx.x >> 6;
        float acc = 0.f;
        for (int q = g; q < NQ; q += 4) {
            int id = ids[q];
            const float* e = emb + (size_t)id * 32;
            float p = eb[j];
#pragma unroll
            for (int k = 0; k < 32; ++k) p = fmaf(e[k], ew[k * 64 + j], p);
            p = fmaf(rssi[q], ew[32 * 64 + j], p);
            acc += fmaxf(p, 0.f);
        }
        zsh[g][j] = acc;
        __syncthreads();
        if (g == 0) {
            float z = (zsh[0][j] + zsh[1][j] + zsh[2][j] + zsh[3][j]) / (float)NQ;
            zq[j] = z;
            zout[j] = z;
        }
        __syncthreads();
        if (g == 0) {
            float cl = 0.f, cr = 0.f;
            for (int k = 0; k < 64; ++k) {
                float zk = zq[k];
                cl = fmaf(zk, B1[(128 + k) * 64 + j], cl);
                cr = fmaf(zk, B2[(128 + k) * 64 + j], cr);
            }
            zout[64 + j] = cl;            // cl
            zout[128 + j] = cr + b0[j];   // crb
        }
        return;
    }

    // ---- gemm0 role: 64-row dual GEMM, K=128, fp16 RAW outputs
    const int tid = threadIdx.x;
    const int cg = tid & 15;
    const int rg = tid >> 4;
    const int row0 = blockIdx.x * 64;

    float acc[4][8];
#pragma unroll
    for (int i = 0; i < 4; ++i)
#pragma unroll
        for (int j = 0; j < 8; ++j) acc[i][j] = 0.f;

    for (int kc = 0; kc < 128; kc += 32) {
#pragma unroll
        for (int i = 0; i < 2; ++i) {
            int vi = i * 256 + tid;
            int r = vi >> 3;
            int k4 = (vi & 7) << 2;
            int row = row0 + r;
            float4 v = make_float4(0.f, 0.f, 0.f, 0.f);
            if (row < N) v = *(const float4*)(A + (size_t)row * 128 + kc + k4);
            *(float4*)&As[r][k4] = v;
        }
#pragma unroll
        for (int i = 0; i < 4; ++i) {
            int vi = i * 256 + tid;
            int k = vi >> 5;
            int c = (vi & 31) << 2;
            const float* sp = (c < 64) ? (B1 + (size_t)(kc + k) * 64 + c)
                                       : (B2 + (size_t)(kc + k) * 64 + (c - 64));
            *(float4*)&Bs[k][c] = *(const float4*)sp;
        }
        __syncthreads();
#pragma unroll
        for (int k4 = 0; k4 < 32; k4 += 4) {
            float4 a4[4];
#pragma unroll
            for (int i = 0; i < 4; ++i)
                a4[i] = *(const float4*)&As[rg * 4 + i][k4];
#pragma unroll
            for (int j = 0; j < 4; ++j) {
                float4 b0v = *(const float4*)&Bs[k4 + j][cg * 8];
                float4 b1v = *(const float4*)&Bs[k4 + j][cg * 8 + 4];
#pragma unroll
                for (int i = 0; i < 4; ++i) {
                    float av = ((const float*)&a4[i])[j];
                    acc[i][0] = fmaf(av, b0v.x, acc[i][0]);
                    acc[i][1] = fmaf(av, b0v.y, acc[i][1]);
                    acc[i][2] = fmaf(av, b0v.z, acc[i][2]);
                    acc[i][3] = fmaf(av, b0v.w, acc[i][3]);
                    acc[i][4] = fmaf(av, b1v.x, acc[i][4]);
                    acc[i][5] = fmaf(av, b1v.y, acc[i][5]);
                    acc[i][6] = fmaf(av, b1v.z, acc[i][6]);
                    acc[i][7] = fmaf(av, b1v.w, acc[i][7]);
                }
            }
        }
        __syncthreads();
    }

    int c0 = cg * 8;
    __half* O; int c;
    if (c0 < 64) { O = O1; c = c0; }
    else         { O = O2; c = c0 - 64; }
#pragma unroll
    for (int i = 0; i < 4; ++i) {
        int row = row0 + rg * 4 + i;
        if (row < N) {
            float2 q[2];
            q[0] = f4_to_h4(make_float4(acc[i][0], acc[i][1], acc[i][2], acc[i][3]));
            q[1] = f4_to_h4(make_float4(acc[i][4], acc[i][5], acc[i][6], acc[i][7]));
            *(float4*)(O + (size_t)row * 64 + c) = *(float4*)q;   // 8 halves = 16B
        }
    }
}

// ---------------- CSR build: scanA (local) + scanC (per-block prefix of bsum) ----------------
__global__ __launch_bounds__(256) void scanA_kernel(const int* __restrict__ deg, int* __restrict__ offs,
                                                    int* __restrict__ bsum, unsigned* __restrict__ red, int N)
{
    __shared__ int sh[256];
    int t = threadIdx.x;
    if (blockIdx.x == 0 && t < 8) red[t] = 0u;
    int i = blockIdx.x * 256 + t;
    int v = (i < N) ? deg[i] : 0;
    sh[t] = v;
    __syncthreads();
#pragma unroll
    for (int d = 1; d < 256; d <<= 1) {
        int u = (t >= d) ? sh[t - d] : 0;
        __syncthreads();
        sh[t] += u;
        __syncthreads();
    }
    if (i < N) offs[i] = sh[t] - v;
    if (t == 255) bsum[blockIdx.x] = sh[255];
}

__global__ __launch_bounds__(256) void scanC_kernel(int* __restrict__ offs, const int* __restrict__ bsum,
                                                    int N, int NB)
{
    __shared__ int sh[256];
    int t = threadIdx.x;
    int bid = blockIdx.x;
    int s = 0;
    for (int j = t; j < bid; j += 256) s += bsum[j];
    sh[t] = s;
    __syncthreads();
#pragma unroll
    for (int d = 128; d >= 1; d >>= 1) {
        if (t < d) sh[t] += sh[t + d];
        __syncthreads();
    }
    int base = sh[0];
    int i = bid * 256 + t;
    if (i < N) offs[i] += base;
    if (bid == NB - 1 && t == 0) offs[N] = base + bsum[NB - 1];
}

// ---------------- atomic-free scatter: srcs[offs[d]+rank[i]] = src[i] (pure stream) ----------
__global__ __launch_bounds__(256) void scatter_kernel(const int* __restrict__ src, const int* __restrict__ dst,
                                                      const int* __restrict__ rank, const int* __restrict__ offs,
                                                      int* __restrict__ srcs, int E)
{
    int i = blockIdx.x * 1024 + threadIdx.x;
#pragma unroll
    for (int it = 0; it < 4; ++it, i += 256) {
        if (i < E) srcs[offs[dst[i]] + rank[i]] = src[i];
    }
}

// ---------------- layer-0 aggregation (fp16 rows: 128B -> half the lines per random row) -----
// h = relu(segsum(m)/clip(deg,1) + [deg>0]*cl + (r_raw + crb)); m,r,hout fp16; accum fp32.
__global__ __launch_bounds__(256) void agg_kernel(
    const __half* __restrict__ m, const __half* __restrict__ r,
    const int* __restrict__ off, const int* __restrict__ srcs,
    const float* __restrict__ cl, const float* __restrict__ crb,
    __half* __restrict__ hout, int N)
{
    const int tid = threadIdx.x;
    const int lane = tid & 63;
    const int wave = tid >> 6;
    const int grp = lane >> 4;
    const int l16 = lane & 15;
    const int node0 = blockIdx.x * 64;

    int offv = off[min(node0 + lane, N)];
    int offend = off[min(node0 + 64, N)];
    float4 cl4 = *(const float4*)(cl + l16 * 4);
    float4 cb4 = *(const float4*)(crb + l16 * 4);

    int e0p = __shfl(offv, wave);
    int e1p = (wave < 63) ? __shfl(offv, wave + 1) : offend;
    int sv = (e0p + lane < e1p) ? srcs[e0p + lane] : 0;

    for (int idx = 0; idx < 16; ++idx) {
        int nn = wave + idx * 4;
        int node = node0 + nn;
        int e0 = __shfl(offv, nn);
        int e1 = (nn < 63) ? __shfl(offv, nn + 1) : offend;
        int cur_sv = sv;
        if (idx < 15) {
            int nx = nn + 4;
            int ne0 = __shfl(offv, nx);
            int ne1 = (nx < 63) ? __shfl(offv, nx + 1) : offend;
            sv = (ne0 + lane < ne1) ? srcs[ne0 + lane] : 0;
        }
        float4 r4 = make_float4(0.f, 0.f, 0.f, 0.f);
        if (node < N) r4 = h4_to_f4(*(const float2*)(r + (size_t)node * 64 + l16 * 4));

        float4 acc4[4];
#pragma unroll
        for (int t = 0; t < 4; ++t) acc4[t] = make_float4(0.f, 0.f, 0.f, 0.f);

        for (int base = e0; base < e1; base += 64) {
            int cnt = min(e1 - base, 64);
            int svs = (base == e0) ? cur_sv : ((base + lane < e1) ? srcs[base + lane] : 0);
            for (int u = 0; u < cnt; u += 16) {
#pragma unroll
                for (int t = 0; t < 4; ++t) {
                    int ei = u + t * 4 + grp;
                    int s = __shfl(svs, ei);
                    if (ei < cnt) {
                        float4 v = h4_to_f4(*(const float2*)(m + (size_t)s * 64 + l16 * 4));
                        acc4[t].x += v.x; acc4[t].y += v.y;
                        acc4[t].z += v.z; acc4[t].w += v.w;
                    }
                }
            }
        }
        float4 tot;
        tot.x = (acc4[0].x + acc4[1].x) + (acc4[2].x + acc4[3].x);
        tot.y = (acc4[0].y + acc4[1].y) + (acc4[2].y + acc4[3].y);
        tot.z = (acc4[0].z + acc4[1].z) + (acc4[2].z + acc4[3].z);
        tot.w = (acc4[0].w + acc4[1].w) + (acc4[2].w + acc4[3].w);
        tot.x += __shfl_xor(tot.x, 16); tot.x += __shfl_xor(tot.x, 32);
        tot.y += __shfl_xor(tot.y, 16); tot.y += __shfl_xor(tot.y, 32);
        tot.z += __shfl_xor(tot.z, 16); tot.z += __shfl_xor(tot.z, 32);
        tot.w += __shfl_xor(tot.w, 16); tot.w += __shfl_xor(tot.w, 32);

        int deg = e1 - e0;
        float inv = 1.f / (float)(deg > 0 ? deg : 1);
        if (lane < 16 && node < N) {
            float cadd = (deg > 0) ? 1.f : 0.f;
            float4 o;
            o.x = fmaxf(fmaf(tot.x, inv, fmaf(cadd, cl4.x, r4.x + cb4.x)), 0.f);
            o.y = fmaxf(fmaf(tot.y, inv, fmaf(cadd, cl4.y, r4.y + cb4.y)), 0.f);
            o.z = fmaxf(fmaf(tot.z, inv, fmaf(cadd, cl4.z, r4.z + cb4.z)), 0.f);
            o.w = fmaxf(fmaf(tot.w, inv, fmaf(cadd, cl4.w, r4.w + cb4.w)), 0.f);
            float2 q = f4_to_h4(o);
            *(float2*)(hout + (size_t)node * 64 + l16 * 4) = q;   // 4 halves = 8B
        }
    }
}

// ---------------- fused SAGE layer (layers 1-2): round-8 structure, fp16 activations ---------
template <bool SCORER>
__global__ __launch_bounds__(256) void sage_fused_kernel(
    const __half* __restrict__ h,
    const int* __restrict__ off, const int* __restrict__ srcs,
    const float* __restrict__ Wl, const float* __restrict__ Wr, const float* __restrict__ bias,
    const float* __restrict__ sw1, const float* __restrict__ sb1,
    const float* __restrict__ sw2, const float* __restrict__ sb2,
    __half* __restrict__ hout, float* __restrict__ sbuf, unsigned* __restrict__ red, int N)
{
    __shared__ float As[32][132];   // 16.9 KB
    __shared__ float Bs[32][64];    // 8 KB
    __shared__ float smax_sh[256];  // 1 KB

    const int tid = threadIdx.x;
    const int lane = tid & 63;
    const int wave = tid >> 6;
    const int grp = lane >> 4;
    const int l16 = lane & 15;
    const int node0 = blockIdx.x * 32;

    int offv = off[min(node0 + lane, N)];   // lanes 0..32 used

    int e0p = __shfl(offv, wave);
    int e1p = __shfl(offv, wave + 1);
    int sv = (e0p + lane < e1p) ? srcs[e0p + lane] : 0;

    for (int idx = 0; idx < 8; ++idx) {
        int nn = wave + idx * 4;
        int node = node0 + nn;
        int e0 = __shfl(offv, nn);
        int e1 = __shfl(offv, nn + 1);
        int cur_sv = sv;
        if (idx < 7) {
            int nx = nn + 4;
            int ne0 = __shfl(offv, nx);
            int ne1 = __shfl(offv, nx + 1);
            sv = (ne0 + lane < ne1) ? srcs[ne0 + lane] : 0;
        }
        float4 hv = make_float4(0.f, 0.f, 0.f, 0.f);
        if (node < N) hv = h4_to_f4(*(const float2*)(h + (size_t)node * 64 + l16 * 4));

        float4 acc4[4];
#pragma unroll
        for (int t = 0; t < 4; ++t) acc4[t] = make_float4(0.f, 0.f, 0.f, 0.f);

        for (int base = e0; base < e1; base += 64) {
            int cnt = min(e1 - base, 64);
            int svs = (base == e0) ? cur_sv : ((base + lane < e1) ? srcs[base + lane] : 0);
            for (int u = 0; u < cnt; u += 16) {
#pragma unroll
                for (int t = 0; t < 4; ++t) {
                    int ei = u + t * 4 + grp;
                    int s = __shfl(svs, ei);
                    if (ei < cnt) {
                        float4 v = h4_to_f4(*(const float2*)(h + (size_t)s * 64 + l16 * 4));
                        acc4[t].x += v.x; acc4[t].y += v.y;
                        acc4[t].z += v.z; acc4[t].w += v.w;
                    }
                }
            }
        }
        float4 tot;
        tot.x = (acc4[0].x + acc4[1].x) + (acc4[2].x + acc4[3].x);
        tot.y = (acc4[0].y + acc4[1].y) + (acc4[2].y + acc4[3].y);
        tot.z = (acc4[0].z + acc4[1].z) + (acc4[2].z + acc4[3].z);
        tot.w = (acc4[0].w + acc4[1].w) + (acc4[2].w + acc4[3].w);
        tot.x += __shfl_xor(tot.x, 16); tot.x += __shfl_xor(tot.x, 32);
        tot.y += __shfl_xor(tot.y, 16); tot.y += __shfl_xor(tot.y, 32);
        tot.z += __shfl_xor(tot.z, 16); tot.z += __shfl_xor(tot.z, 32);
        tot.w += __shfl_xor(tot.w, 16); tot.w += __shfl_xor(tot.w, 32);

        int deg = e1 - e0;
        float inv = 1.f / (float)(deg > 0 ? deg : 1);
        if (lane < 16) {
            float4 g4 = make_float4(tot.x * inv, tot.y * inv, tot.z * inv, tot.w * inv);
            *(float4*)&As[nn][l16 * 4] = g4;
            *(float4*)&As[nn][64 + l16 * 4] = hv;
        }
    }

    // ---- Phase 2: [32x128] @ [128x64], thread tile 2 rows x 4 cols (round-8 verbatim)
    const int cg = tid & 15;
    const int rg = tid >> 4;
    float acc[2][4];
#pragma unroll
    for (int i = 0; i < 2; ++i)
#pragma unroll
        for (int j = 0; j < 4; ++j) acc[i][j] = 0.f;

    for (int kc = 0; kc < 128; kc += 32) {
#pragma unroll
        for (int i = 0; i < 2; ++i) {
            int vi = i * 256 + tid;
            int k = vi >> 4;
            int c = (vi & 15) << 2;
            int kg = kc + k;
            const float* wp = (kg < 64) ? (Wl + (size_t)kg * 64 + c)
                                        : (Wr + (size_t)(kg - 64) * 64 + c);
            *(float4*)&Bs[k][c] = *(const float4*)wp;
        }
        __syncthreads();
#pragma unroll
        for (int k4 = 0; k4 < 32; k4 += 4) {
            float4 a4[2];
#pragma unroll
            for (int i = 0; i < 2; ++i)
                a4[i] = *(const float4*)&As[rg * 2 + i][kc + k4];   // broadcast
#pragma unroll
            for (int j = 0; j < 4; ++j) {
                float4 bv = *(const float4*)&Bs[k4 + j][cg * 4];
#pragma unroll
                for (int i = 0; i < 2; ++i) {
                    float av = ((const float*)&a4[i])[j];
                    acc[i][0] = fmaf(av, bv.x, acc[i][0]);
                    acc[i][1] = fmaf(av, bv.y, acc[i][1]);
                    acc[i][2] = fmaf(av, bv.z, acc[i][2]);
                    acc[i][3] = fmaf(av, bv.w, acc[i][3]);
                }
            }
        }
        __syncthreads();
    }

    float4 b4 = *(const float4*)(bias + cg * 4);

    if (!SCORER) {
#pragma unroll
        for (int i = 0; i < 2; ++i) {
            int row = node0 + rg * 2 + i;
            if (row < N) {
                float4 o;
                o.x = fmaxf(acc[i][0] + b4.x, 0.f);
                o.y = fmaxf(acc[i][1] + b4.y, 0.f);
                o.z = fmaxf(acc[i][2] + b4.z, 0.f);
                o.w = fmaxf(acc[i][3] + b4.w, 0.f);
                float2 q = f4_to_h4(o);
                *(float2*)(hout + (size_t)row * 64 + cg * 4) = q;   // 4 halves = 8B
            }
        }
        return;
    }

    // ---- SCORER: h2 -> As cols 0..63, then s = relu(h2@w1+b1)@w2 + b2 (h2 never hits HBM)
#pragma unroll
    for (int i = 0; i < 2; ++i) {
        float4 t;
        t.x = fmaxf(acc[i][0] + b4.x, 0.f);
        t.y = fmaxf(acc[i][1] + b4.y, 0.f);
        t.z = fmaxf(acc[i][2] + b4.z, 0.f);
        t.w = fmaxf(acc[i][3] + b4.w, 0.f);
        *(float4*)&As[rg * 2 + i][cg * 4] = t;
    }
    __syncthreads();

    float acc2[2][4];
#pragma unroll
    for (int i = 0; i < 2; ++i)
#pragma unroll
        for (int j = 0; j < 4; ++j) acc2[i][j] = 0.f;

    for (int kc = 0; kc < 64; kc += 32) {
#pragma unroll
        for (int i = 0; i < 2; ++i) {
            int vi = i * 256 + tid;
            int k = vi >> 4;
            int c = (vi & 15) << 2;
            *(float4*)&Bs[k][c] = *(const float4*)(sw1 + (size_t)(kc + k) * 64 + c);
        }
        __syncthreads();
#pragma unroll
        for (int k4 = 0; k4 < 32; k4 += 4) {
            float4 a4[2];
#pragma unroll
            for (int i = 0; i < 2; ++i)
                a4[i] = *(const float4*)&As[rg * 2 + i][kc + k4];
#pragma unroll
            for (int j = 0; j < 4; ++j) {
                float4 bv = *(const float4*)&Bs[k4 + j][cg * 4];
#pragma unroll
                for (int i = 0; i < 2; ++i) {
                    float av = ((const float*)&a4[i])[j];
                    acc2[i][0] = fmaf(av, bv.x, acc2[i][0]);
                    acc2[i][1] = fmaf(av, bv.y, acc2[i][1]);
                    acc2[i][2] = fmaf(av, bv.z, acc2[i][2]);
                    acc2[i][3] = fmaf(av, bv.w, acc2[i][3]);
                }
            }
        }
        __syncthreads();
    }

    float4 s1b = *(const float4*)(sb1 + cg * 4);
    float4 w24 = *(const float4*)(sw2 + cg * 4);
    float bb = sb2[0];
    float svals[2];
#pragma unroll
    for (int i = 0; i < 2; ++i) {
        float p = fmaxf(acc2[i][0] + s1b.x, 0.f) * w24.x;
        p = fmaf(fmaxf(acc2[i][1] + s1b.y, 0.f), w24.y, p);
        p = fmaf(fmaxf(acc2[i][2] + s1b.z, 0.f), w24.z, p);
        p = fmaf(fmaxf(acc2[i][3] + s1b.w, 0.f), w24.w, p);
#pragma unroll
        for (int d = 1; d <= 8; d <<= 1) p += __shfl_xor(p, d, 64);
        svals[i] = p;
    }
    float smx = -FLT_MAX;
    if (cg == 0) {
#pragma unroll
        for (int i = 0; i < 2; ++i) {
            int row = node0 + rg * 2 + i;
            if (row < N) {
                float s = svals[i] + bb;
                sbuf[row] = s;
                smx = fmaxf(smx, s);
            }
        }
    }
    smax_sh[tid] = smx;
    __syncthreads();
    for (int d = 128; d >= 1; d >>= 1) {
        if (tid < d) smax_sh[tid] = fmaxf(smax_sh[tid], smax_sh[tid + d]);
        __syncthreads();
    }
    if (tid == 0) atomicMax(red, enc_f(smax_sh[0]));
}

// ---------------- softmax: sum + finalize in ONE kernel (ticket spin, 128 resident blocks) ----
__global__ __launch_bounds__(256) void sumfinal_kernel(const float* __restrict__ s, const float* __restrict__ pos,
                                                       unsigned* __restrict__ red, float* __restrict__ out, int N)
{
    float mx = dec_f(red[0]);
    float se = 0.f, px = 0.f, py = 0.f;
    for (int i = blockIdx.x * blockDim.x + threadIdx.x; i < N; i += gridDim.x * blockDim.x) {
        float e = expf(s[i] - mx);
        se += e;
        px = fmaf(e, pos[2 * i], px);
        py = fmaf(e, pos[2 * i + 1], py);
    }
#pragma unroll
    for (int d = 32; d >= 1; d >>= 1) {
        se += __shfl_xor(se, d, 64);
        px += __shfl_xor(px, d, 64);
        py += __shfl_xor(py, d, 64);
    }
    if ((threadIdx.x & 63) == 0) {
        atomicAdd((float*)red + 1, se);
        atomicAdd((float*)red + 2, px);
        atomicAdd((float*)red + 3, py);
    }
    __threadfence();
    if (threadIdx.x == 0) {
        __hip_atomic_fetch_add(&red[4], 1u, __ATOMIC_ACQ_REL, __HIP_MEMORY_SCOPE_AGENT);
        while (__hip_atomic_load(&red[4], __ATOMIC_ACQUIRE, __HIP_MEMORY_SCOPE_AGENT) < (unsigned)gridDim.x) {}
    }
    __syncthreads();
    float S  = __uint_as_float(__hip_atomic_load(&red[1], __ATOMIC_RELAXED, __HIP_MEMORY_SCOPE_AGENT));
    float PX = __uint_as_float(__hip_atomic_load(&red[2], __ATOMIC_RELAXED, __HIP_MEMORY_SCOPE_AGENT));
    float PY = __uint_as_float(__hip_atomic_load(&red[3], __ATOMIC_RELAXED, __HIP_MEMORY_SCOPE_AGENT));
    float invS = 1.f / S;
    for (int i = blockIdx.x * blockDim.x + threadIdx.x; i < N; i += gridDim.x * blockDim.x)
        out[2 + i] = expf(s[i] - mx) * invS;
    if (blockIdx.x == 0 && threadIdx.x == 0) {
        out[0] = PX * invS;
        out[1] = PY * invS;
    }
}

extern "C" void kernel_launch(void* const* d_in, const int* in_sizes, int n_in,
                              void* d_out, int out_size, void* d_ws, size_t ws_size,
                              hipStream_t stream)
{
    const float* x    = (const float*)d_in[0];
    const float* pos  = (const float*)d_in[1];
    const int*   ei   = (const int*)d_in[2];
    const int*   qids = (const int*)d_in[3];
    const float* qrs  = (const float*)d_in[4];
    const float* emb  = (const float*)d_in[5];
    const float* ew   = (const float*)d_in[6];
    const float* eb   = (const float*)d_in[7];
    const float* Wl0  = (const float*)d_in[8];
    const float* Wr0  = (const float*)d_in[9];
    const float* b0   = (const float*)d_in[10];
    const float* Wl1  = (const float*)d_in[11];
    const float* Wr1  = (const float*)d_in[12];
    const float* b1   = (const float*)d_in[13];
    const float* Wl2  = (const float*)d_in[14];
    const float* Wr2  = (const float*)d_in[15];
    const float* b2   = (const float*)d_in[16];
    const float* sw1  = (const float*)d_in[17];
    const float* sb1  = (const float*)d_in[18];
    const float* sw2  = (const float*)d_in[19];
    const float* sb2  = (const float*)d_in[20];

    const int N  = in_sizes[0] / 128;
    const int E  = in_sizes[2] / 2;
    const int NQ = in_sizes[3];
    const int NB = (N + 255) / 256;

    char* base = (char*)d_ws;
    size_t wsoff = 0;
    auto take = [&](size_t bytes) -> char* {
        char* p = base + wsoff;
        wsoff = (wsoff + bytes + 255) & ~(size_t)255;
        return p;
    };
    int*      deg    = (int*)take((size_t)N * 4);
    int*      offs   = (int*)take((size_t)(N + 1) * 4);
    int*      rank   = (int*)take((size_t)E * 4);
    int*      bsum   = (int*)take((size_t)NB * 4);
    int*      srcs   = (int*)take((size_t)E * 4);
    float*    zout   = (float*)take(192 * 4);   // zq[64], cl[64], crb[64]
    unsigned* red    = (unsigned*)take(32);     // [0]=max [1]=sumexp [2]=px [3]=py [4]=ticket
    __half*   mbuf   = (__half*)take((size_t)N * 64 * 2);
    __half*   rbuf   = (__half*)take((size_t)N * 64 * 2);
    __half*   hbuf   = (__half*)take((size_t)N * 64 * 2);
    float*    sbuf   = (float*)take((size_t)N * 4);
    (void)ws_size; (void)n_in; (void)out_size;

    const int* esrc = ei;
    const int* edst = ei + E;

    hipMemsetAsync(deg, 0, (size_t)N * 4, stream);

    int schunks = (E + 4095) / 4096;
    int nCount = schunks * 8;
    int g64 = (N + 63) / 64;
    int g32 = (N + 31) / 32;

    // launch 1: gemm0 (independent) + count+rank (atomic-bound) + encoder, overlapped
    fused0_kernel<<<g64 + nCount + 1, 256, 0, stream>>>(edst, deg, rank, E, N,
                                                        x, Wl0, Wr0, mbuf, rbuf, g64, nCount,
                                                        qids, qrs, emb, ew, eb, b0, zout, NQ);
    scanA_kernel<<<NB, 256, 0, stream>>>(deg, offs, bsum, red, N);
    scanC_kernel<<<NB, 256, 0, stream>>>(offs, bsum, N, NB);
    // atomic-free scatter (pure stream)
    scatter_kernel<<<(E + 1023) / 1024, 256, 0, stream>>>(esrc, edst, rank, offs, srcs, E);
    // layer 0 aggregation (adds crb + cl here; gemm0 wrote raw products)
    agg_kernel<<<g64, 256, 0, stream>>>(mbuf, rbuf, offs, srcs, zout + 64, zout + 128, hbuf, N);
    // layer 1: fused agg-first + gemm (hbuf -> mbuf)
    sage_fused_kernel<false><<<g32, 256, 0, stream>>>(hbuf, offs, srcs, Wl1, Wr1, b1,
                                                      nullptr, nullptr, nullptr, nullptr,
                                                      mbuf, nullptr, nullptr, N);
    // layer 2 + scorer fused (mbuf -> sbuf, red[0])
    sage_fused_kernel<true><<<g32, 256, 0, stream>>>(mbuf, offs, srcs, Wl2, Wr2, b2,
                                                     sw1, sb1, sw2, sb2,
                                                     nullptr, sbuf, red, N);
    // softmax sum + finalize (single launch, internal grid sync)
    sumfinal_kernel<<<128, 256, 0, stream>>>(sbuf, pos, red, (float*)d_out, N);
}

// Round 12
// 357.370 us; speedup vs baseline: 1.4641x; 1.0558x over previous
//
#include <hip/hip_runtime.h>
#include <hip/hip_fp16.h>
#include <cmath>
#include <cfloat>

#define DEV __device__ __forceinline__

DEV unsigned enc_f(float x) { unsigned u = __float_as_uint(x); return (u >> 31) ? ~u : (u | 0x80000000u); }
DEV float dec_f(unsigned u) { return __uint_as_float((u >> 31) ? (u & 0x7FFFFFFFu) : ~u); }

// 4 halves packed in a float2 <-> float4 converters
DEV float4 h4_to_f4(float2 raw) {
    __half2 a = *(__half2*)&raw.x, b = *(__half2*)&raw.y;
    float2 fa = __half22float2(a), fb = __half22float2(b);
    return make_float4(fa.x, fa.y, fb.x, fb.y);
}
DEV float2 f4_to_h4(float4 v) {
    __half2 a = __floats2half2_rn(v.x, v.y), b = __floats2half2_rn(v.z, v.w);
    float2 r; *(__half2*)&r.x = a; *(__half2*)&r.y = b; return r;
}

// ---------------- merged launch 1: layer-0 GEMM + XCD-partitioned count+rank + encoder -------
// gemm0 writes RAW products as fp16 (O1=x@Wl0top, O2=x@Wr0top); bias/crb added in agg.
__global__ __launch_bounds__(256) void fused0_kernel(
    const int* __restrict__ dst, int* __restrict__ deg, int* __restrict__ rank, int E, int N,
    const float* __restrict__ A, const float* __restrict__ B1, const float* __restrict__ B2,
    __half* __restrict__ O1, __half* __restrict__ O2, int nGemm, int nCount,
    const int* __restrict__ ids, const float* __restrict__ rssi,
    const float* __restrict__ emb, const float* __restrict__ ew, const float* __restrict__ eb,
    const float* __restrict__ b0, float* __restrict__ zout, int NQ)
{
    __shared__ float As[64][36];    // 9.2 KB
    __shared__ float Bs[32][128];   // 16.4 KB

    if (blockIdx.x >= (unsigned)nGemm) {
        if (blockIdx.x < (unsigned)(nGemm + nCount)) {
            // ---- count + rank role (XCD-partitioned by dst range)
            const int cbid = blockIdx.x - nGemm;
            const int part = cbid & 7;
            const int chunk = cbid >> 3;
            const int npart = (N + 7) >> 3;
            const int lo = part * npart;
            const int hi = min(lo + npart, N);
            const int base = chunk * 4096 + threadIdx.x;
#pragma unroll
            for (int it = 0; it < 16; ++it) {
                int i = base + it * 256;
                if (i < E) {
                    int d = dst[i];
                    if (d >= lo && d < hi) rank[i] = atomicAdd(&deg[d], 1);
                }
            }
            return;
        }
        // ---- encoder role (1 block); zsh/zq aliased into As
        float (*zsh)[64] = (float(*)[64])&As[0][0];
        float* zq = &As[16][0];
        int j = threadIdx.x & 63;
        int g = threadIdx.x >> 6;
        float acc = 0.f;
        for (int q = g; q < NQ; q += 4) {
            int id = ids[q];
            const float* e = emb + (size_t)id * 32;
            float p = eb[j];
#pragma unroll
            for (int k = 0; k < 32; ++k) p = fmaf(e[k], ew[k * 64 + j], p);
            p = fmaf(rssi[q], ew[32 * 64 + j], p);
            acc += fmaxf(p, 0.f);
        }
        zsh[g][j] = acc;
        __syncthreads();
        if (g == 0) {
            float z = (zsh[0][j] + zsh[1][j] + zsh[2][j] + zsh[3][j]) / (float)NQ;
            zq[j] = z;
            zout[j] = z;
        }
        __syncthreads();
        if (g == 0) {
            float cl = 0.f, cr = 0.f;
            for (int k = 0; k < 64; ++k) {
                float zk = zq[k];
                cl = fmaf(zk, B1[(128 + k) * 64 + j], cl);
                cr = fmaf(zk, B2[(128 + k) * 64 + j], cr);
            }
            zout[64 + j] = cl;            // cl
            zout[128 + j] = cr + b0[j];   // crb
        }
        return;
    }

    // ---- gemm0 role: 64-row dual GEMM, K=128, fp16 RAW outputs
    const int tid = threadIdx.x;
    const int cg = tid & 15;
    const int rg = tid >> 4;
    const int row0 = blockIdx.x * 64;

    float acc[4][8];
#pragma unroll
    for (int i = 0; i < 4; ++i)
#pragma unroll
        for (int j = 0; j < 8; ++j) acc[i][j] = 0.f;

    for (int kc = 0; kc < 128; kc += 32) {
#pragma unroll
        for (int i = 0; i < 2; ++i) {
            int vi = i * 256 + tid;
            int r = vi >> 3;
            int k4 = (vi & 7) << 2;
            int row = row0 + r;
            float4 v = make_float4(0.f, 0.f, 0.f, 0.f);
            if (row < N) v = *(const float4*)(A + (size_t)row * 128 + kc + k4);
            *(float4*)&As[r][k4] = v;
        }
#pragma unroll
        for (int i = 0; i < 4; ++i) {
            int vi = i * 256 + tid;
            int k = vi >> 5;
            int c = (vi & 31) << 2;
            const float* sp = (c < 64) ? (B1 + (size_t)(kc + k) * 64 + c)
                                       : (B2 + (size_t)(kc + k) * 64 + (c - 64));
            *(float4*)&Bs[k][c] = *(const float4*)sp;
        }
        __syncthreads();
#pragma unroll
        for (int k4 = 0; k4 < 32; k4 += 4) {
            float4 a4[4];
#pragma unroll
            for (int i = 0; i < 4; ++i)
                a4[i] = *(const float4*)&As[rg * 4 + i][k4];
#pragma unroll
            for (int j = 0; j < 4; ++j) {
                float4 b0v = *(const float4*)&Bs[k4 + j][cg * 8];
                float4 b1v = *(const float4*)&Bs[k4 + j][cg * 8 + 4];
#pragma unroll
                for (int i = 0; i < 4; ++i) {
                    float av = ((const float*)&a4[i])[j];
                    acc[i][0] = fmaf(av, b0v.x, acc[i][0]);
                    acc[i][1] = fmaf(av, b0v.y, acc[i][1]);
                    acc[i][2] = fmaf(av, b0v.z, acc[i][2]);
                    acc[i][3] = fmaf(av, b0v.w, acc[i][3]);
                    acc[i][4] = fmaf(av, b1v.x, acc[i][4]);
                    acc[i][5] = fmaf(av, b1v.y, acc[i][5]);
                    acc[i][6] = fmaf(av, b1v.z, acc[i][6]);
                    acc[i][7] = fmaf(av, b1v.w, acc[i][7]);
                }
            }
        }
        __syncthreads();
    }

    int c0 = cg * 8;
    __half* O; int c;
    if (c0 < 64) { O = O1; c = c0; }
    else         { O = O2; c = c0 - 64; }
#pragma unroll
    for (int i = 0; i < 4; ++i) {
        int row = row0 + rg * 4 + i;
        if (row < N) {
            float2 q[2];
            q[0] = f4_to_h4(make_float4(acc[i][0], acc[i][1], acc[i][2], acc[i][3]));
            q[1] = f4_to_h4(make_float4(acc[i][4], acc[i][5], acc[i][6], acc[i][7]));
            *(float4*)(O + (size_t)row * 64 + c) = *(float4*)q;   // 8 halves = 16B
        }
    }
}

// ---------------- CSR build: scanA (local) + scanC (per-block prefix of bsum) ----------------
__global__ __launch_bounds__(256) void scanA_kernel(const int* __restrict__ deg, int* __restrict__ offs,
                                                    int* __restrict__ bsum, unsigned* __restrict__ red, int N)
{
    __shared__ int sh[256];
    int t = threadIdx.x;
    if (blockIdx.x == 0 && t < 8) red[t] = 0u;
    int i = blockIdx.x * 256 + t;
    int v = (i < N) ? deg[i] : 0;
    sh[t] = v;
    __syncthreads();
#pragma unroll
    for (int d = 1; d < 256; d <<= 1) {
        int u = (t >= d) ? sh[t - d] : 0;
        __syncthreads();
        sh[t] += u;
        __syncthreads();
    }
    if (i < N) offs[i] = sh[t] - v;
    if (t == 255) bsum[blockIdx.x] = sh[255];
}

__global__ __launch_bounds__(256) void scanC_kernel(int* __restrict__ offs, const int* __restrict__ bsum,
                                                    int N, int NB)
{
    __shared__ int sh[256];
    int t = threadIdx.x;
    int bid = blockIdx.x;
    int s = 0;
    for (int j = t; j < bid; j += 256) s += bsum[j];
    sh[t] = s;
    __syncthreads();
#pragma unroll
    for (int d = 128; d >= 1; d >>= 1) {
        if (t < d) sh[t] += sh[t + d];
        __syncthreads();
    }
    int base = sh[0];
    int i = bid * 256 + t;
    if (i < N) offs[i] += base;
    if (bid == NB - 1 && t == 0) offs[N] = base + bsum[NB - 1];
}

// ---------------- atomic-free scatter: srcs[offs[d]+rank[i]] = src[i] (pure stream) ----------
__global__ __launch_bounds__(256) void scatter_kernel(const int* __restrict__ src, const int* __restrict__ dst,
                                                      const int* __restrict__ rank, const int* __restrict__ offs,
                                                      int* __restrict__ srcs, int E)
{
    int i = blockIdx.x * 1024 + threadIdx.x;
#pragma unroll
    for (int it = 0; it < 4; ++it, i += 256) {
        if (i < E) srcs[offs[dst[i]] + rank[i]] = src[i];
    }
}

// ---------------- layer-0 aggregation (fp16 rows; fp32 accum) -- unchanged from r11 ----------
__global__ __launch_bounds__(256) void agg_kernel(
    const __half* __restrict__ m, const __half* __restrict__ r,
    const int* __restrict__ off, const int* __restrict__ srcs,
    const float* __restrict__ cl, const float* __restrict__ crb,
    __half* __restrict__ hout, int N)
{
    const int tid = threadIdx.x;
    const int lane = tid & 63;
    const int wave = tid >> 6;
    const int grp = lane >> 4;
    const int l16 = lane & 15;
    const int node0 = blockIdx.x * 64;

    int offv = off[min(node0 + lane, N)];
    int offend = off[min(node0 + 64, N)];
    float4 cl4 = *(const float4*)(cl + l16 * 4);
    float4 cb4 = *(const float4*)(crb + l16 * 4);

    int e0p = __shfl(offv, wave);
    int e1p = (wave < 63) ? __shfl(offv, wave + 1) : offend;
    int sv = (e0p + lane < e1p) ? srcs[e0p + lane] : 0;

    for (int idx = 0; idx < 16; ++idx) {
        int nn = wave + idx * 4;
        int node = node0 + nn;
        int e0 = __shfl(offv, nn);
        int e1 = (nn < 63) ? __shfl(offv, nn + 1) : offend;
        int cur_sv = sv;
        if (idx < 15) {
            int nx = nn + 4;
            int ne0 = __shfl(offv, nx);
            int ne1 = (nx < 63) ? __shfl(offv, nx + 1) : offend;
            sv = (ne0 + lane < ne1) ? srcs[ne0 + lane] : 0;
        }
        float4 r4 = make_float4(0.f, 0.f, 0.f, 0.f);
        if (node < N) r4 = h4_to_f4(*(const float2*)(r + (size_t)node * 64 + l16 * 4));

        float4 acc4[4];
#pragma unroll
        for (int t = 0; t < 4; ++t) acc4[t] = make_float4(0.f, 0.f, 0.f, 0.f);

        for (int base = e0; base < e1; base += 64) {
            int cnt = min(e1 - base, 64);
            int svs = (base == e0) ? cur_sv : ((base + lane < e1) ? srcs[base + lane] : 0);
            for (int u = 0; u < cnt; u += 16) {
#pragma unroll
                for (int t = 0; t < 4; ++t) {
                    int ei = u + t * 4 + grp;
                    int s = __shfl(svs, ei);
                    if (ei < cnt) {
                        float4 v = h4_to_f4(*(const float2*)(m + (size_t)s * 64 + l16 * 4));
                        acc4[t].x += v.x; acc4[t].y += v.y;
                        acc4[t].z += v.z; acc4[t].w += v.w;
                    }
                }
            }
        }
        float4 tot;
        tot.x = (acc4[0].x + acc4[1].x) + (acc4[2].x + acc4[3].x);
        tot.y = (acc4[0].y + acc4[1].y) + (acc4[2].y + acc4[3].y);
        tot.z = (acc4[0].z + acc4[1].z) + (acc4[2].z + acc4[3].z);
        tot.w = (acc4[0].w + acc4[1].w) + (acc4[2].w + acc4[3].w);
        tot.x += __shfl_xor(tot.x, 16); tot.x += __shfl_xor(tot.x, 32);
        tot.y += __shfl_xor(tot.y, 16); tot.y += __shfl_xor(tot.y, 32);
        tot.z += __shfl_xor(tot.z, 16); tot.z += __shfl_xor(tot.z, 32);
        tot.w += __shfl_xor(tot.w, 16); tot.w += __shfl_xor(tot.w, 32);

        int deg = e1 - e0;
        float inv = 1.f / (float)(deg > 0 ? deg : 1);
        if (lane < 16 && node < N) {
            float cadd = (deg > 0) ? 1.f : 0.f;
            float4 o;
            o.x = fmaxf(fmaf(tot.x, inv, fmaf(cadd, cl4.x, r4.x + cb4.x)), 0.f);
            o.y = fmaxf(fmaf(tot.y, inv, fmaf(cadd, cl4.y, r4.y + cb4.y)), 0.f);
            o.z = fmaxf(fmaf(tot.z, inv, fmaf(cadd, cl4.z, r4.z + cb4.z)), 0.f);
            o.w = fmaxf(fmaf(tot.w, inv, fmaf(cadd, cl4.w, r4.w + cb4.w)), 0.f);
            float2 q = f4_to_h4(o);
            *(float2*)(hout + (size_t)node * 64 + l16 * 4) = q;   // 4 halves = 8B
        }
    }
}

// ---------------- fused SAGE layer: r11 structure, As in fp16 -> 17.3 KB LDS, 8 blocks/CU ----
// Unconfounded occupancy test: gather loop and phase-2 barrier structure byte-identical to the
// 73us kernel; only the As element type changes (float->half, cvt on phase-2 read).
template <bool SCORER>
__global__ __launch_bounds__(256) void sage_fused_kernel(
    const __half* __restrict__ h,
    const int* __restrict__ off, const int* __restrict__ srcs,
    const float* __restrict__ Wl, const float* __restrict__ Wr, const float* __restrict__ bias,
    const float* __restrict__ sw1, const float* __restrict__ sb1,
    const float* __restrict__ sw2, const float* __restrict__ sb2,
    __half* __restrict__ hout, float* __restrict__ sbuf, unsigned* __restrict__ red, int N)
{
    __shared__ __half As[32][132];  // 8.4 KB: [gathered-mean | own-h] per node, fp16
    __shared__ float Bs[32][64];    // 8 KB
    __shared__ float smax_sh[256];  // 1 KB -> total 17.3 KB -> 8 blocks/CU

    const int tid = threadIdx.x;
    const int lane = tid & 63;
    const int wave = tid >> 6;
    const int grp = lane >> 4;
    const int l16 = lane & 15;
    const int node0 = blockIdx.x * 32;

    int offv = off[min(node0 + lane, N)];   // lanes 0..32 used

    int e0p = __shfl(offv, wave);
    int e1p = __shfl(offv, wave + 1);
    int sv = (e0p + lane < e1p) ? srcs[e0p + lane] : 0;

    for (int idx = 0; idx < 8; ++idx) {
        int nn = wave + idx * 4;
        int node = node0 + nn;
        int e0 = __shfl(offv, nn);
        int e1 = __shfl(offv, nn + 1);
        int cur_sv = sv;
        if (idx < 7) {
            int nx = nn + 4;
            int ne0 = __shfl(offv, nx);
            int ne1 = __shfl(offv, nx + 1);
            sv = (ne0 + lane < ne1) ? srcs[ne0 + lane] : 0;
        }
        float2 hraw = make_float2(0.f, 0.f);   // 4 halves, bit-zero == fp16 zeros
        if (node < N) hraw = *(const float2*)(h + (size_t)node * 64 + l16 * 4);

        float4 acc4[4];
#pragma unroll
        for (int t = 0; t < 4; ++t) acc4[t] = make_float4(0.f, 0.f, 0.f, 0.f);

        for (int base = e0; base < e1; base += 64) {
            int cnt = min(e1 - base, 64);
            int svs = (base == e0) ? cur_sv : ((base + lane < e1) ? srcs[base + lane] : 0);
            for (int u = 0; u < cnt; u += 16) {
#pragma unroll
                for (int t = 0; t < 4; ++t) {
                    int ei = u + t * 4 + grp;
                    int s = __shfl(svs, ei);
                    if (ei < cnt) {
                        float4 v = h4_to_f4(*(const float2*)(h + (size_t)s * 64 + l16 * 4));
                        acc4[t].x += v.x; acc4[t].y += v.y;
                        acc4[t].z += v.z; acc4[t].w += v.w;
                    }
                }
            }
        }
        float4 tot;
        tot.x = (acc4[0].x + acc4[1].x) + (acc4[2].x + acc4[3].x);
        tot.y = (acc4[0].y + acc4[1].y) + (acc4[2].y + acc4[3].y);
        tot.z = (acc4[0].z + acc4[1].z) + (acc4[2].z + acc4[3].z);
        tot.w = (acc4[0].w + acc4[1].w) + (acc4[2].w + acc4[3].w);
        tot.x += __shfl_xor(tot.x, 16); tot.x += __shfl_xor(tot.x, 32);
        tot.y += __shfl_xor(tot.y, 16); tot.y += __shfl_xor(tot.y, 32);
        tot.z += __shfl_xor(tot.z, 16); tot.z += __shfl_xor(tot.z, 32);
        tot.w += __shfl_xor(tot.w, 16); tot.w += __shfl_xor(tot.w, 32);

        int deg = e1 - e0;
        float inv = 1.f / (float)(deg > 0 ? deg : 1);
        if (lane < 16) {
            float4 g4 = make_float4(tot.x * inv, tot.y * inv, tot.z * inv, tot.w * inv);
            *(float2*)&As[nn][l16 * 4] = f4_to_h4(g4);
            *(float2*)&As[nn][64 + l16 * 4] = hraw;
        }
    }

    // ---- Phase 2: [32x128] @ [128x64], thread tile 2 rows x 4 cols (structure unchanged)
    const int cg = tid & 15;
    const int rg = tid >> 4;
    float acc[2][4];
#pragma unroll
    for (int i = 0; i < 2; ++i)
#pragma unroll
        for (int j = 0; j < 4; ++j) acc[i][j] = 0.f;

    for (int kc = 0; kc < 128; kc += 32) {
#pragma unroll
        for (int i = 0; i < 2; ++i) {
            int vi = i * 256 + tid;
            int k = vi >> 4;
            int c = (vi & 15) << 2;
            int kg = kc + k;
            const float* wp = (kg < 64) ? (Wl + (size_t)kg * 64 + c)
                                        : (Wr + (size_t)(kg - 64) * 64 + c);
            *(float4*)&Bs[k][c] = *(const float4*)wp;
        }
        __syncthreads();
#pragma unroll
        for (int k4 = 0; k4 < 32; k4 += 4) {
            float4 a4[2];
#pragma unroll
            for (int i = 0; i < 2; ++i)
                a4[i] = h4_to_f4(*(const float2*)&As[rg * 2 + i][kc + k4]);   // broadcast + cvt
#pragma unroll
            for (int j = 0; j < 4; ++j) {
                float4 bv = *(const float4*)&Bs[k4 + j][cg * 4];
#pragma unroll
                for (int i = 0; i < 2; ++i) {
                    float av = ((const float*)&a4[i])[j];
                    acc[i][0] = fmaf(av, bv.x, acc[i][0]);
                    acc[i][1] = fmaf(av, bv.y, acc[i][1]);
                    acc[i][2] = fmaf(av, bv.z, acc[i][2]);
                    acc[i][3] = fmaf(av, bv.w, acc[i][3]);
                }
            }
        }
        __syncthreads();
    }

    float4 b4 = *(const float4*)(bias + cg * 4);

    if (!SCORER) {
#pragma unroll
        for (int i = 0; i < 2; ++i) {
            int row = node0 + rg * 2 + i;
            if (row < N) {
                float4 o;
                o.x = fmaxf(acc[i][0] + b4.x, 0.f);
                o.y = fmaxf(acc[i][1] + b4.y, 0.f);
                o.z = fmaxf(acc[i][2] + b4.z, 0.f);
                o.w = fmaxf(acc[i][3] + b4.w, 0.f);
                float2 q = f4_to_h4(o);
                *(float2*)(hout + (size_t)row * 64 + cg * 4) = q;   // 4 halves = 8B
            }
        }
        return;
    }

    // ---- SCORER: h2 -> As cols 0..63 (fp16), then s = relu(h2@w1+b1)@w2 + b2
#pragma unroll
    for (int i = 0; i < 2; ++i) {
        float4 t;
        t.x = fmaxf(acc[i][0] + b4.x, 0.f);
        t.y = fmaxf(acc[i][1] + b4.y, 0.f);
        t.z = fmaxf(acc[i][2] + b4.z, 0.f);
        t.w = fmaxf(acc[i][3] + b4.w, 0.f);
        *(float2*)&As[rg * 2 + i][cg * 4] = f4_to_h4(t);
    }
    __syncthreads();

    float acc2[2][4];
#pragma unroll
    for (int i = 0; i < 2; ++i)
#pragma unroll
        for (int j = 0; j < 4; ++j) acc2[i][j] = 0.f;

    for (int kc = 0; kc < 64; kc += 32) {
#pragma unroll
        for (int i = 0; i < 2; ++i) {
            int vi = i * 256 + tid;
            int k = vi >> 4;
            int c = (vi & 15) << 2;
            *(float4*)&Bs[k][c] = *(const float4*)(sw1 + (size_t)(kc + k) * 64 + c);
        }
        __syncthreads();
#pragma unroll
        for (int k4 = 0; k4 < 32; k4 += 4) {
            float4 a4[2];
#pragma unroll
            for (int i = 0; i < 2; ++i)
                a4[i] = h4_to_f4(*(const float2*)&As[rg * 2 + i][kc + k4]);
#pragma unroll
            for (int j = 0; j < 4; ++j) {
                float4 bv = *(const float4*)&Bs[k4 + j][cg * 4];
#pragma unroll
                for (int i = 0; i < 2; ++i) {
                    float av = ((const float*)&a4[i])[j];
                    acc2[i][0] = fmaf(av, bv.x, acc2[i][0]);
                    acc2[i][1] = fmaf(av, bv.y, acc2[i][1]);
                    acc2[i][2] = fmaf(av, bv.z, acc2[i][2]);
                    acc2[i][3] = fmaf(av, bv.w, acc2[i][3]);
                }
            }
        }
        __syncthreads();
    }

    float4 s1b = *(const float4*)(sb1 + cg * 4);
    float4 w24 = *(const float4*)(sw2 + cg * 4);
    float bb = sb2[0];
    float svals[2];
#pragma unroll
    for (int i = 0; i < 2; ++i) {
        float p = fmaxf(acc2[i][0] + s1b.x, 0.f) * w24.x;
        p = fmaf(fmaxf(acc2[i][1] + s1b.y, 0.f), w24.y, p);
        p = fmaf(fmaxf(acc2[i][2] + s1b.z, 0.f), w24.z, p);
        p = fmaf(fmaxf(acc2[i][3] + s1b.w, 0.f), w24.w, p);
#pragma unroll
        for (int d = 1; d <= 8; d <<= 1) p += __shfl_xor(p, d, 64);
        svals[i] = p;
    }
    float smx = -FLT_MAX;
    if (cg == 0) {
#pragma unroll
        for (int i = 0; i < 2; ++i) {
            int row = node0 + rg * 2 + i;
            if (row < N) {
                float s = svals[i] + bb;
                sbuf[row] = s;
                smx = fmaxf(smx, s);
            }
        }
    }
    smax_sh[tid] = smx;
    __syncthreads();
    for (int d = 128; d >= 1; d >>= 1) {
        if (tid < d) smax_sh[tid] = fmaxf(smax_sh[tid], smax_sh[tid + d]);
        __syncthreads();
    }
    if (tid == 0) atomicMax(red, enc_f(smax_sh[0]));
}

// ---------------- softmax: sum + finalize in ONE kernel (ticket spin, 128 resident blocks) ----
__global__ __launch_bounds__(256) void sumfinal_kernel(const float* __restrict__ s, const float* __restrict__ pos,
                                                       unsigned* __restrict__ red, float* __restrict__ out, int N)
{
    float mx = dec_f(red[0]);
    float se = 0.f, px = 0.f, py = 0.f;
    for (int i = blockIdx.x * blockDim.x + threadIdx.x; i < N; i += gridDim.x * blockDim.x) {
        float e = expf(s[i] - mx);
        se += e;
        px = fmaf(e, pos[2 * i], px);
        py = fmaf(e, pos[2 * i + 1], py);
    }
#pragma unroll
    for (int d = 32; d >= 1; d >>= 1) {
        se += __shfl_xor(se, d, 64);
        px += __shfl_xor(px, d, 64);
        py += __shfl_xor(py, d, 64);
    }
    if ((threadIdx.x & 63) == 0) {
        atomicAdd((float*)red + 1, se);
        atomicAdd((float*)red + 2, px);
        atomicAdd((float*)red + 3, py);
    }
    __threadfence();
    if (threadIdx.x == 0) {
        __hip_atomic_fetch_add(&red[4], 1u, __ATOMIC_ACQ_REL, __HIP_MEMORY_SCOPE_AGENT);
        while (__hip_atomic_load(&red[4], __ATOMIC_ACQUIRE, __HIP_MEMORY_SCOPE_AGENT) < (unsigned)gridDim.x) {}
    }
    __syncthreads();
    float S  = __uint_as_float(__hip_atomic_load(&red[1], __ATOMIC_RELAXED, __HIP_MEMORY_SCOPE_AGENT));
    float PX = __uint_as_float(__hip_atomic_load(&red[2], __ATOMIC_RELAXED, __HIP_MEMORY_SCOPE_AGENT));
    float PY = __uint_as_float(__hip_atomic_load(&red[3], __ATOMIC_RELAXED, __HIP_MEMORY_SCOPE_AGENT));
    float invS = 1.f / S;
    for (int i = blockIdx.x * blockDim.x + threadIdx.x; i < N; i += gridDim.x * blockDim.x)
        out[2 + i] = expf(s[i] - mx) * invS;
    if (blockIdx.x == 0 && threadIdx.x == 0) {
        out[0] = PX * invS;
        out[1] = PY * invS;
    }
}

extern "C" void kernel_launch(void* const* d_in, const int* in_sizes, int n_in,
                              void* d_out, int out_size, void* d_ws, size_t ws_size,
                              hipStream_t stream)
{
    const float* x    = (const float*)d_in[0];
    const float* pos  = (const float*)d_in[1];
    const int*   ei   = (const int*)d_in[2];
    const int*   qids = (const int*)d_in[3];
    const float* qrs  = (const float*)d_in[4];
    const float* emb  = (const float*)d_in[5];
    const float* ew   = (const float*)d_in[6];
    const float* eb   = (const float*)d_in[7];
    const float* Wl0  = (const float*)d_in[8];
    const float* Wr0  = (const float*)d_in[9];
    const float* b0   = (const float*)d_in[10];
    const float* Wl1  = (const float*)d_in[11];
    const float* Wr1  = (const float*)d_in[12];
    const float* b1   = (const float*)d_in[13];
    const float* Wl2  = (const float*)d_in[14];
    const float* Wr2  = (const float*)d_in[15];
    const float* b2   = (const float*)d_in[16];
    const float* sw1  = (const float*)d_in[17];
    const float* sb1  = (const float*)d_in[18];
    const float* sw2  = (const float*)d_in[19];
    const float* sb2  = (const float*)d_in[20];

    const int N  = in_sizes[0] / 128;
    const int E  = in_sizes[2] / 2;
    const int NQ = in_sizes[3];
    const int NB = (N + 255) / 256;

    char* base = (char*)d_ws;
    size_t wsoff = 0;
    auto take = [&](size_t bytes) -> char* {
        char* p = base + wsoff;
        wsoff = (wsoff + bytes + 255) & ~(size_t)255;
        return p;
    };
    int*      deg    = (int*)take((size_t)N * 4);
    int*      offs   = (int*)take((size_t)(N + 1) * 4);
    int*      rank   = (int*)take((size_t)E * 4);
    int*      bsum   = (int*)take((size_t)NB * 4);
    int*      srcs   = (int*)take((size_t)E * 4);
    float*    zout   = (float*)take(192 * 4);   // zq[64], cl[64], crb[64]
    unsigned* red    = (unsigned*)take(32);     // [0]=max [1]=sumexp [2]=px [3]=py [4]=ticket
    __half*   mbuf   = (__half*)take((size_t)N * 64 * 2);
    __half*   rbuf   = (__half*)take((size_t)N * 64 * 2);
    __half*   hbuf   = (__half*)take((size_t)N * 64 * 2);
    float*    sbuf   = (float*)take((size_t)N * 4);
    (void)ws_size; (void)n_in; (void)out_size;

    const int* esrc = ei;
    const int* edst = ei + E;

    hipMemsetAsync(deg, 0, (size_t)N * 4, stream);

    int schunks = (E + 4095) / 4096;
    int nCount = schunks * 8;
    int g64 = (N + 63) / 64;
    int g32 = (N + 31) / 32;

    // launch 1: gemm0 (independent) + count+rank (atomic-bound) + encoder, overlapped
    fused0_kernel<<<g64 + nCount + 1, 256, 0, stream>>>(edst, deg, rank, E, N,
                                                        x, Wl0, Wr0, mbuf, rbuf, g64, nCount,
                                                        qids, qrs, emb, ew, eb, b0, zout, NQ);
    scanA_kernel<<<NB, 256, 0, stream>>>(deg, offs, bsum, red, N);
    scanC_kernel<<<NB, 256, 0, stream>>>(offs, bsum, N, NB);
    // atomic-free scatter (pure stream)
    scatter_kernel<<<(E + 1023) / 1024, 256, 0, stream>>>(esrc, edst, rank, offs, srcs, E);
    // layer 0 aggregation (adds crb + cl here; gemm0 wrote raw products)
    agg_kernel<<<g64, 256, 0, stream>>>(mbuf, rbuf, offs, srcs, zout + 64, zout + 128, hbuf, N);
    // layer 1: fused agg-first + gemm (hbuf -> mbuf)
    sage_fused_kernel<false><<<g32, 256, 0, stream>>>(hbuf, offs, srcs, Wl1, Wr1, b1,
                                                      nullptr, nullptr, nullptr, nullptr,
                                                      mbuf, nullptr, nullptr, N);
    // layer 2 + scorer fused (mbuf -> sbuf, red[0])
    sage_fused_kernel<true><<<g32, 256, 0, stream>>>(mbuf, offs, srcs, Wl2, Wr2, b2,
                                                     sw1, sb1, sw2, sb2,
                                                     nullptr, sbuf, red, N);
    // softmax sum + finalize (single launch, internal grid sync)
    sumfinal_kernel<<<128, 256, 0, stream>>>(sbuf, pos, red, (float*)d_out, N);
}